// Round 1
// baseline (183.582 us; speedup 1.0000x reference)
//
#include <hip/hip_runtime.h>
#include <hip/hip_bf16.h>

// Problem constants
#define NB    16
#define NC    1024
#define NF    4096
#define MROWS 65536      // NB*NF
#define CIN   256
#define CSK   128
#define DIN   384        // CIN + CSK
#define CHID  256
#define BN_EPS 1e-5f

typedef __attribute__((ext_vector_type(8))) short bf16x8;
typedef __attribute__((ext_vector_type(4))) float f32x4;

__device__ __forceinline__ unsigned short f2bfu(float f) {
  __hip_bfloat16 h = __float2bfloat16(f);
  return __builtin_bit_cast(unsigned short, h);
}

__device__ __forceinline__ void load_lds16(const void* g, void* lds) {
  __builtin_amdgcn_global_load_lds(
      (const __attribute__((address_space(1))) unsigned int*)g,
      (__attribute__((address_space(3))) unsigned int*)lds, 16, 0, 0);
}

// ---------------------------------------------------------------------------
// K1: kNN interpolate + concat -> h0 (MROWS x 384, bf16)
// One wave per fine point. Coarse positions staged in LDS (SoA).
// ---------------------------------------------------------------------------
__global__ __launch_bounds__(256) void knn_interp_kernel(
    const float* __restrict__ x,        // (NB*NC, 256)
    const float* __restrict__ pos,      // (NB*NC, 3)
    const float* __restrict__ x_skip,   // (NB*NF, 128)
    const float* __restrict__ pos_skip, // (NB*NF, 3)
    __hip_bfloat16* __restrict__ h0)    // (MROWS, 384)
{
  __shared__ float px[NC], py[NC], pz[NC];
  const int bid = blockIdx.x;
  const int tid = threadIdx.x;
  const int wid = tid >> 6;
  const int lane = tid & 63;
  const int f0 = bid * 4;
  const int b = f0 >> 12;            // f0 / NF

  for (int j = tid; j < NC; j += 256) {
    const float* p = pos + (size_t)(b * NC + j) * 3;
    px[j] = p[0]; py[j] = p[1]; pz[j] = p[2];
  }
  __syncthreads();

  const int f = f0 + wid;
  const float* pf = pos_skip + (size_t)f * 3;
  const float fx = pf[0], fy = pf[1], fz = pf[2];

  float d2l[16];
#pragma unroll
  for (int t = 0; t < 16; ++t) {
    int j = t * 64 + lane;
    float dx = fx - px[j], dy = fy - py[j], dz = fz - pz[j];
    // match reference rounding: no fma contraction
    d2l[t] = __fadd_rn(__fadd_rn(__fmul_rn(dx, dx), __fmul_rn(dy, dy)),
                       __fmul_rn(dz, dz));
  }

  float kd[3]; int kj[3];
#pragma unroll
  for (int k = 0; k < 3; ++k) {
    float bd = 3.4e38f; int bt = 0;
#pragma unroll
    for (int t = 0; t < 16; ++t)
      if (d2l[t] < bd) { bd = d2l[t]; bt = t; }
    int bj = bt * 64 + lane;
#pragma unroll
    for (int off = 32; off > 0; off >>= 1) {
      float od = __shfl_xor(bd, off);
      int   oj = __shfl_xor(bj, off);
      if (od < bd || (od == bd && oj < bj)) { bd = od; bj = oj; }
    }
    kd[k] = bd; kj[k] = bj;
#pragma unroll
    for (int t = 0; t < 16; ++t)
      if (t * 64 + lane == bj) d2l[t] = 3.4e38f;
  }

  float w0 = 1.f / fmaxf(kd[0], 1e-16f);
  float w1 = 1.f / fmaxf(kd[1], 1e-16f);
  float w2 = 1.f / fmaxf(kd[2], 1e-16f);
  const float inv = 1.f / (w0 + w1 + w2);
  w0 *= inv; w1 *= inv; w2 *= inv;

  const float4* r0 = (const float4*)(x + (size_t)(b * NC + kj[0]) * CIN);
  const float4* r1 = (const float4*)(x + (size_t)(b * NC + kj[1]) * CIN);
  const float4* r2 = (const float4*)(x + (size_t)(b * NC + kj[2]) * CIN);
  float4 a0 = r0[lane], a1 = r1[lane], a2 = r2[lane];
  float4 v;
  v.x = w0 * a0.x + w1 * a1.x + w2 * a2.x;
  v.y = w0 * a0.y + w1 * a1.y + w2 * a2.y;
  v.z = w0 * a0.z + w1 * a1.z + w2 * a2.z;
  v.w = w0 * a0.w + w1 * a1.w + w2 * a2.w;

  __hip_bfloat16* orow = h0 + (size_t)f * DIN;
  ushort4 o;
  o.x = f2bfu(v.x); o.y = f2bfu(v.y); o.z = f2bfu(v.z); o.w = f2bfu(v.w);
  ((ushort4*)orow)[lane] = o;

  if (lane < 32) {
    float4 s = ((const float4*)(x_skip + (size_t)f * CSK))[lane];
    ushort4 os;
    os.x = f2bfu(s.x); os.y = f2bfu(s.y); os.z = f2bfu(s.z); os.w = f2bfu(s.w);
    ((ushort4*)(orow + CIN))[lane] = os;
  }
}

// ---------------------------------------------------------------------------
// Weight prep kernels
// ---------------------------------------------------------------------------
__global__ void prep_w1_kernel(const float* __restrict__ W1,
                               __hip_bfloat16* __restrict__ W1t) {
  int c = blockIdx.x, n = threadIdx.x;   // c in [0,384), n in [0,256)
  W1t[(size_t)n * DIN + c] = __float2bfloat16(W1[(size_t)c * CHID + n]);
}

__global__ void prep_w2_kernel(const float* __restrict__ W2,
                               const float* __restrict__ scale1,
                               __hip_bfloat16* __restrict__ W2t) {
  int c = blockIdx.x, n = threadIdx.x;   // c,n in [0,256)
  W2t[(size_t)n * CHID + c] =
      __float2bfloat16(scale1[c] * W2[(size_t)c * CHID + n]);
}

__global__ void prep_b2_kernel(const float* __restrict__ W2,
                               const float* __restrict__ shift1,
                               const float* __restrict__ b2,
                               float* __restrict__ b2p) {
  int n = threadIdx.x;
  float s = b2[n];
  for (int c = 0; c < CHID; ++c) s += shift1[c] * W2[(size_t)c * CHID + n];
  b2p[n] = s;
}

__global__ void zero_stats_kernel(float* __restrict__ p) {
  p[blockIdx.x * blockDim.x + threadIdx.x] = 0.f;
}

// ---------------------------------------------------------------------------
// GEMM: C(M x 256) = relu(A(M x KD) @ Bt^T + bias). 128x128 tile, BK=32,
// 4 waves (2x2 of 64x64), global_load_lds staging, 16x16x32 bf16 MFMA.
// ---------------------------------------------------------------------------
template<int KD, bool OUT_BF16>
__global__ __launch_bounds__(256) void gemm_bias_relu(
    const __hip_bfloat16* __restrict__ A,   // M x KD
    const __hip_bfloat16* __restrict__ Bt,  // 256 x KD (row n = column n of B)
    const float* __restrict__ bias,         // 256
    void* __restrict__ out)                 // M x 256
{
  __shared__ __hip_bfloat16 As[128 * 32];
  __shared__ __hip_bfloat16 Bs[128 * 32];
  const int tid = threadIdx.x;
  const int wid = tid >> 6, lane = tid & 63;
  const int bid = blockIdx.x;
  const int bm = bid >> 1, bn = bid & 1;
  const int wr = wid >> 1, wc = wid & 1;
  const int la = lane & 15, lk = lane >> 4;

  f32x4 acc[4][4] = {};

  const int rA = tid >> 2;            // 0..63
  const int c8 = (tid & 3) * 8;
  const __hip_bfloat16* gA0 = A + (size_t)(bm * 128 + rA) * KD + c8;
  const __hip_bfloat16* gA1 = gA0 + (size_t)64 * KD;
  const __hip_bfloat16* gB0 = Bt + (size_t)(bn * 128 + rA) * KD + c8;
  const __hip_bfloat16* gB1 = gB0 + (size_t)64 * KD;
  char* ldsA = (char*)As + wid * 1024;   // wave-uniform dest base
  char* ldsB = (char*)Bs + wid * 1024;

  const int nIter = KD / 32;
  for (int it = 0; it < nIter; ++it) {
    const int k0 = it * 32;
    load_lds16(gA0 + k0, ldsA);
    load_lds16(gA1 + k0, ldsA + 4096);
    load_lds16(gB0 + k0, ldsB);
    load_lds16(gB1 + k0, ldsB + 4096);
    __syncthreads();

    bf16x8 af[4], bfr[4];
#pragma unroll
    for (int m = 0; m < 4; ++m)
      af[m] = *(const bf16x8*)(As + (wr * 64 + m * 16 + la) * 32 + lk * 8);
#pragma unroll
    for (int n = 0; n < 4; ++n)
      bfr[n] = *(const bf16x8*)(Bs + (wc * 64 + n * 16 + la) * 32 + lk * 8);
#pragma unroll
    for (int m = 0; m < 4; ++m)
#pragma unroll
      for (int n = 0; n < 4; ++n)
        acc[m][n] = __builtin_amdgcn_mfma_f32_16x16x32_bf16(
            af[m], bfr[n], acc[m][n], 0, 0, 0);
    __syncthreads();
  }

  const int rowBase = bm * 128 + wr * 64 + lk * 4;
  const int colBase = bn * 128 + wc * 64 + la;
#pragma unroll
  for (int n = 0; n < 4; ++n) {
    const int col = colBase + n * 16;
    const float bs = bias[col];
#pragma unroll
    for (int m = 0; m < 4; ++m) {
      const int row = rowBase + m * 16;
#pragma unroll
      for (int j = 0; j < 4; ++j) {
        float v = acc[m][n][j] + bs;
        v = fmaxf(v, 0.f);
        if constexpr (OUT_BF16)
          ((__hip_bfloat16*)out)[(size_t)(row + j) * 256 + col] =
              __float2bfloat16(v);
        else
          ((float*)out)[(size_t)(row + j) * 256 + col] = v;
      }
    }
  }
}

// ---------------------------------------------------------------------------
// BatchNorm column reduce: per-block partial sums over 256 rows + atomics
// ---------------------------------------------------------------------------
template<bool BF16IN>
__global__ __launch_bounds__(256) void bn_reduce_kernel(
    const void* __restrict__ Z, float* __restrict__ sum,
    float* __restrict__ sumsq) {
  const int c = threadIdx.x;
  const size_t r0 = (size_t)blockIdx.x * 256;
  float s = 0.f, s2 = 0.f;
  for (int r = 0; r < 256; ++r) {
    float v;
    if constexpr (BF16IN)
      v = __bfloat162float(((const __hip_bfloat16*)Z)[(r0 + r) * 256 + c]);
    else
      v = ((const float*)Z)[(r0 + r) * 256 + c];
    s += v; s2 += v * v;
  }
  atomicAdd(&sum[c], s);
  atomicAdd(&sumsq[c], s2);
}

__global__ void bn_finalize_kernel(const float* __restrict__ sum,
                                   const float* __restrict__ sumsq,
                                   const float* __restrict__ g,
                                   const float* __restrict__ be,
                                   float* __restrict__ scale,
                                   float* __restrict__ shift) {
  const int c = threadIdx.x;
  const float m = sum[c] * (1.f / MROWS);
  const float var = sumsq[c] * (1.f / MROWS) - m * m;
  const float sc = g[c] * rsqrtf(var + BN_EPS);
  scale[c] = sc;
  shift[c] = be[c] - m * sc;
}

__global__ __launch_bounds__(256) void bn_apply_kernel(
    float* __restrict__ Z, const float* __restrict__ scale,
    const float* __restrict__ shift) {
  const size_t i4 = (size_t)blockIdx.x * 256 + threadIdx.x;  // float4 index
  float4 v = ((float4*)Z)[i4];
  const int c = (int)((i4 * 4) & 255);
  const float4 sc = *(const float4*)(scale + c);
  const float4 sh = *(const float4*)(shift + c);
  v.x = v.x * sc.x + sh.x;
  v.y = v.y * sc.y + sh.y;
  v.z = v.z * sc.z + sh.z;
  v.w = v.w * sc.w + sh.w;
  ((float4*)Z)[i4] = v;
}

// ---------------------------------------------------------------------------
extern "C" void kernel_launch(void* const* d_in, const int* in_sizes, int n_in,
                              void* d_out, int out_size, void* d_ws,
                              size_t ws_size, hipStream_t stream) {
  (void)in_sizes; (void)n_in; (void)out_size; (void)ws_size;
  const float* x        = (const float*)d_in[0];
  const float* pos      = (const float*)d_in[1];
  const float* x_skip   = (const float*)d_in[3];
  const float* pos_skip = (const float*)d_in[4];
  const float* W1  = (const float*)d_in[6];
  const float* b1  = (const float*)d_in[7];
  const float* g1  = (const float*)d_in[8];
  const float* be1 = (const float*)d_in[9];
  const float* W2  = (const float*)d_in[10];
  const float* b2  = (const float*)d_in[11];
  const float* g2  = (const float*)d_in[12];
  const float* be2 = (const float*)d_in[13];
  float* out = (float*)d_out;

  char* ws = (char*)d_ws;
  // Workspace layout (bytes)
  __hip_bfloat16* h0  = (__hip_bfloat16*)(ws);                    // 50331648
  __hip_bfloat16* W1t = (__hip_bfloat16*)(ws + 50331648);         // 196608
  __hip_bfloat16* z1  = (__hip_bfloat16*)(ws + 50528256);         // 33554432
  __hip_bfloat16* W2t = (__hip_bfloat16*)(ws + 84082688);         // 131072
  float* b2p    = (float*)(ws + 84213760);                        // 1024
  float* stats  = (float*)(ws + 84214784);                        // 4096: sum1,sq1,sum2,sq2
  float* scale1 = (float*)(ws + 84218880);                        // 1024
  float* shift1 = scale1 + 256;
  float* scale2 = scale1 + 512;
  float* shift2 = scale1 + 768;

  zero_stats_kernel<<<1, 1024, 0, stream>>>(stats);
  prep_w1_kernel<<<384, 256, 0, stream>>>(W1, W1t);
  knn_interp_kernel<<<16384, 256, 0, stream>>>(x, pos, x_skip, pos_skip, h0);
  gemm_bias_relu<DIN, true><<<1024, 256, 0, stream>>>(h0, W1t, b1, z1);
  bn_reduce_kernel<true><<<256, 256, 0, stream>>>(z1, stats, stats + 256);
  bn_finalize_kernel<<<1, 256, 0, stream>>>(stats, stats + 256, g1, be1,
                                            scale1, shift1);
  prep_w2_kernel<<<256, 256, 0, stream>>>(W2, scale1, W2t);
  prep_b2_kernel<<<1, 256, 0, stream>>>(W2, shift1, b2, b2p);
  gemm_bias_relu<CHID, false><<<1024, 256, 0, stream>>>(z1, W2t, b2p, out);
  bn_reduce_kernel<false><<<256, 256, 0, stream>>>(out, stats + 512,
                                                   stats + 768);
  bn_finalize_kernel<<<1, 256, 0, stream>>>(stats + 512, stats + 768, g2, be2,
                                            scale2, shift2);
  bn_apply_kernel<<<16384, 256, 0, stream>>>(out, scale2, shift2);
}

// Round 2
// 153.105 us; speedup vs baseline: 1.1991x; 1.1991x over previous
//
#include <hip/hip_runtime.h>
#include <hip/hip_bf16.h>

// Problem constants
#define NB    16
#define NC    1024
#define NF    4096
#define MROWS 65536      // NB*NF
#define CIN   256
#define CSK   128
#define DIN   384        // CIN + CSK
#define CHID  256
#define BN_EPS 1e-5f

typedef __attribute__((ext_vector_type(8))) short bf16x8;
typedef __attribute__((ext_vector_type(4))) float f32x4;

__device__ __forceinline__ unsigned short f2bfu(float f) {
  __hip_bfloat16 h = __float2bfloat16(f);
  return __builtin_bit_cast(unsigned short, h);
}
__device__ __forceinline__ float bfu2f(unsigned short u) {
  unsigned int w = ((unsigned int)u) << 16;
  return __builtin_bit_cast(float, w);
}

__device__ __forceinline__ void load_lds16(const void* g, void* lds) {
  __builtin_amdgcn_global_load_lds(
      (const __attribute__((address_space(1))) unsigned int*)g,
      (__attribute__((address_space(3))) unsigned int*)lds, 16, 0, 0);
}

// ---------------------------------------------------------------------------
// K1: kNN interpolate + concat -> h0 (MROWS x 384, bf16)
// Lane-per-point; 4 waves split the 1024 candidates (256 each); in-register
// sorted top-3 via v_min/v_med3 + index cndmasks; strict-< keeps exact
// lax.top_k tie semantics (lower index wins on equal distance).
// ---------------------------------------------------------------------------
__global__ __launch_bounds__(256) void knn_interp_kernel(
    const float* __restrict__ x,        // (NB*NC, 256)
    const float* __restrict__ pos,      // (NB*NC, 3)
    const float* __restrict__ x_skip,   // (NB*NF, 128)
    const float* __restrict__ pos_skip, // (NB*NF, 3)
    __hip_bfloat16* __restrict__ h0)    // (MROWS, 384)
{
  __shared__ float4 cpos[NC];          // 16 KB
  __shared__ float  md[4][64][3];
  __shared__ int    mi[4][64][3];
  __shared__ float  fw[64][3];
  __shared__ int    fi[64][3];

  const int tid = threadIdx.x, wid = tid >> 6, lane = tid & 63;
  const int f0 = blockIdx.x * 64;      // 64 fine points per block
  const int b  = f0 >> 12;             // batch (4096 fine pts / batch)

  const float* pb = pos + (size_t)b * NC * 3;
  for (int j = tid; j < NC; j += 256)
    cpos[j] = make_float4(pb[3 * j], pb[3 * j + 1], pb[3 * j + 2], 0.f);
  __syncthreads();

  const int f = f0 + lane;
  const float* pf = pos_skip + (size_t)f * 3;
  const float fx = pf[0], fy = pf[1], fz = pf[2];

  float b0 = 3.4e38f, b1 = 3.4e38f, b2v = 3.4e38f;
  int   i0 = 0, i1 = 0, i2 = 0;
  const int jbase = wid * 256;
#pragma unroll 4
  for (int jj = 0; jj < 256; ++jj) {
    const float4 c = cpos[jbase + jj];
    const float dx = __fsub_rn(fx, c.x);
    const float dy = __fsub_rn(fy, c.y);
    const float dz = __fsub_rn(fz, c.z);
    const float d2 = __fadd_rn(
        __fadd_rn(__fmul_rn(dx, dx), __fmul_rn(dy, dy)), __fmul_rn(dz, dz));
    const int j = jbase + jj;
    const bool c0 = d2 < b0, c1 = d2 < b1, c2 = d2 < b2v;
    const float nb1 = __builtin_amdgcn_fmed3f(d2, b0, b1);
    const float nb2 = __builtin_amdgcn_fmed3f(d2, b1, b2v);
    i2  = c1 ? i1 : (c2 ? j : i2);
    i1  = c0 ? i0 : (c1 ? j : i1);
    i0  = c0 ? j : i0;
    b2v = nb2;
    b1  = nb1;
    b0  = fminf(d2, b0);
  }
  md[wid][lane][0] = b0;  md[wid][lane][1] = b1;  md[wid][lane][2] = b2v;
  mi[wid][lane][0] = i0;  mi[wid][lane][1] = i1;  mi[wid][lane][2] = i2;
  __syncthreads();

  if (wid == 0) {
    // merge quarters 1..3 (all their indices > everything held): strict-<
#pragma unroll
    for (int q = 1; q < 4; ++q) {
#pragma unroll
      for (int e = 0; e < 3; ++e) {
        const float d = md[q][lane][e];
        const int   j = mi[q][lane][e];
        const bool c0 = d < b0, c1 = d < b1, c2 = d < b2v;
        const float nb1 = __builtin_amdgcn_fmed3f(d, b0, b1);
        const float nb2 = __builtin_amdgcn_fmed3f(d, b1, b2v);
        i2  = c1 ? i1 : (c2 ? j : i2);
        i1  = c0 ? i0 : (c1 ? j : i1);
        i0  = c0 ? j : i0;
        b2v = nb2;
        b1  = nb1;
        b0  = fminf(d, b0);
      }
    }
    float w0 = 1.f / fmaxf(b0, 1e-16f);
    float w1 = 1.f / fmaxf(b1, 1e-16f);
    float w2 = 1.f / fmaxf(b2v, 1e-16f);
    const float inv = 1.f / (w0 + w1 + w2);
    fw[lane][0] = w0 * inv; fw[lane][1] = w1 * inv; fw[lane][2] = w2 * inv;
    fi[lane][0] = i0; fi[lane][1] = i1; fi[lane][2] = i2;
  }
  __syncthreads();

  // gather: wave w handles points p = w*16 .. w*16+15 (coalesced per point)
  for (int pp = 0; pp < 16; ++pp) {
    const int p = wid * 16 + pp;
    const float w0 = fw[p][0], w1 = fw[p][1], w2 = fw[p][2];
    const int j0 = fi[p][0], j1 = fi[p][1], j2 = fi[p][2];
    const float4* r0 = (const float4*)(x + (size_t)(b * NC + j0) * CIN);
    const float4* r1 = (const float4*)(x + (size_t)(b * NC + j1) * CIN);
    const float4* r2 = (const float4*)(x + (size_t)(b * NC + j2) * CIN);
    const float4 a0 = r0[lane], a1 = r1[lane], a2 = r2[lane];
    float4 v;
    v.x = w0 * a0.x + w1 * a1.x + w2 * a2.x;
    v.y = w0 * a0.y + w1 * a1.y + w2 * a2.y;
    v.z = w0 * a0.z + w1 * a1.z + w2 * a2.z;
    v.w = w0 * a0.w + w1 * a1.w + w2 * a2.w;
    __hip_bfloat16* orow = h0 + (size_t)(f0 + p) * DIN;
    ushort4 o;
    o.x = f2bfu(v.x); o.y = f2bfu(v.y); o.z = f2bfu(v.z); o.w = f2bfu(v.w);
    ((ushort4*)orow)[lane] = o;
    // skip copy: 128 f32 -> bf16, 2 per lane
    const float2 s = ((const float2*)(x_skip + (size_t)(f0 + p) * CSK))[lane];
    const unsigned int packed =
        ((unsigned int)f2bfu(s.y) << 16) | (unsigned int)f2bfu(s.x);
    ((unsigned int*)(orow + CIN))[lane] = packed;
  }
}

// ---------------------------------------------------------------------------
// Weight prep kernels
// ---------------------------------------------------------------------------
__global__ void prep_w1_kernel(const float* __restrict__ W1,
                               __hip_bfloat16* __restrict__ W1t,
                               float* __restrict__ stats) {
  int c = blockIdx.x, n = threadIdx.x;   // c in [0,384), n in [0,256)
  if (blockIdx.x == 0) {
    for (int k = threadIdx.x; k < 1024; k += 256) stats[k] = 0.f;
  }
  W1t[(size_t)n * DIN + c] = __float2bfloat16(W1[(size_t)c * CHID + n]);
}

__global__ void prep_w2_kernel(const float* __restrict__ W2,
                               const float* __restrict__ scale1,
                               __hip_bfloat16* __restrict__ W2t) {
  int c = blockIdx.x, n = threadIdx.x;   // c,n in [0,256)
  W2t[(size_t)n * CHID + c] =
      __float2bfloat16(scale1[c] * W2[(size_t)c * CHID + n]);
}

__global__ __launch_bounds__(64) void prep_b2_kernel(
    const float* __restrict__ W2, const float* __restrict__ shift1,
    const float* __restrict__ b2, float* __restrict__ b2p) {
  const int n = blockIdx.x, l = threadIdx.x;
  float s = 0.f;
  for (int c = l; c < CHID; c += 64) s += shift1[c] * W2[(size_t)c * CHID + n];
#pragma unroll
  for (int off = 32; off > 0; off >>= 1) s += __shfl_down(s, off);
  if (l == 0) b2p[n] = s + b2[n];
}

// ---------------------------------------------------------------------------
// GEMM: Z(M x 256) = relu(A(M x KD) @ Bt^T + bias), bf16 out, fused
// per-column sum/sumsq accumulation for BatchNorm stats.
// 128x128 tile, BK=32, 4 waves (2x2 of 64x64), global_load_lds staging.
// ---------------------------------------------------------------------------
template<int KD>
__global__ __launch_bounds__(256) void gemm_bias_relu(
    const __hip_bfloat16* __restrict__ A,   // M x KD
    const __hip_bfloat16* __restrict__ Bt,  // 256 x KD
    const float* __restrict__ bias,         // 256
    __hip_bfloat16* __restrict__ out,       // M x 256 (bf16)
    float* __restrict__ gsum,               // 256
    float* __restrict__ gsq)                // 256
{
  __shared__ __hip_bfloat16 As[128 * 32];
  __shared__ __hip_bfloat16 Bs[128 * 32];
  __shared__ float ssum[128], ssq[128];
  const int tid = threadIdx.x;
  const int wid = tid >> 6, lane = tid & 63;
  const int bid = blockIdx.x;
  const int bm = bid >> 1, bn = bid & 1;
  const int wr = wid >> 1, wc = wid & 1;
  const int la = lane & 15, lk = lane >> 4;

  if (tid < 128) { ssum[tid] = 0.f; ssq[tid] = 0.f; }

  f32x4 acc[4][4] = {};

  const int rA = tid >> 2;            // 0..63
  const int c8 = (tid & 3) * 8;
  const __hip_bfloat16* gA0 = A + (size_t)(bm * 128 + rA) * KD + c8;
  const __hip_bfloat16* gA1 = gA0 + (size_t)64 * KD;
  const __hip_bfloat16* gB0 = Bt + (size_t)(bn * 128 + rA) * KD + c8;
  const __hip_bfloat16* gB1 = gB0 + (size_t)64 * KD;
  char* ldsA = (char*)As + wid * 1024;   // wave-uniform dest base
  char* ldsB = (char*)Bs + wid * 1024;

  const int nIter = KD / 32;
  for (int it = 0; it < nIter; ++it) {
    const int k0 = it * 32;
    load_lds16(gA0 + k0, ldsA);
    load_lds16(gA1 + k0, ldsA + 4096);
    load_lds16(gB0 + k0, ldsB);
    load_lds16(gB1 + k0, ldsB + 4096);
    __syncthreads();

    bf16x8 af[4], bfr[4];
#pragma unroll
    for (int m = 0; m < 4; ++m)
      af[m] = *(const bf16x8*)(As + (wr * 64 + m * 16 + la) * 32 + lk * 8);
#pragma unroll
    for (int n = 0; n < 4; ++n)
      bfr[n] = *(const bf16x8*)(Bs + (wc * 64 + n * 16 + la) * 32 + lk * 8);
#pragma unroll
    for (int m = 0; m < 4; ++m)
#pragma unroll
      for (int n = 0; n < 4; ++n)
        acc[m][n] = __builtin_amdgcn_mfma_f32_16x16x32_bf16(
            af[m], bfr[n], acc[m][n], 0, 0, 0);
    __syncthreads();
  }

  const int rowBase = bm * 128 + wr * 64 + lk * 4;
  const int lcolBase = wc * 64 + la;
#pragma unroll
  for (int n = 0; n < 4; ++n) {
    const int lcol = lcolBase + n * 16;
    const int col = bn * 128 + lcol;
    const float bs = bias[col];
    float ls = 0.f, ls2 = 0.f;
#pragma unroll
    for (int m = 0; m < 4; ++m) {
      const int row = rowBase + m * 16;
#pragma unroll
      for (int j = 0; j < 4; ++j) {
        float v = acc[m][n][j] + bs;
        v = fmaxf(v, 0.f);
        ls += v; ls2 += v * v;
        out[(size_t)(row + j) * 256 + col] = __float2bfloat16(v);
      }
    }
    atomicAdd(&ssum[lcol], ls);
    atomicAdd(&ssq[lcol], ls2);
  }
  __syncthreads();
  if (tid < 128) {
    atomicAdd(&gsum[bn * 128 + tid], ssum[tid]);
    atomicAdd(&gsq[bn * 128 + tid], ssq[tid]);
  }
}

// ---------------------------------------------------------------------------
__global__ void bn_finalize_kernel(const float* __restrict__ sum,
                                   const float* __restrict__ sumsq,
                                   const float* __restrict__ g,
                                   const float* __restrict__ be,
                                   float* __restrict__ scale,
                                   float* __restrict__ shift) {
  const int c = threadIdx.x;
  const float m = sum[c] * (1.f / MROWS);
  const float var = sumsq[c] * (1.f / MROWS) - m * m;
  const float sc = g[c] * rsqrtf(var + BN_EPS);
  scale[c] = sc;
  shift[c] = be[c] - m * sc;
}

// bn apply: read bf16 z2, write f32 out. 8 elems per thread.
__global__ __launch_bounds__(256) void bn_apply_kernel(
    const __hip_bfloat16* __restrict__ Z, const float* __restrict__ scale,
    const float* __restrict__ shift, float* __restrict__ out) {
  const size_t i8 = (size_t)blockIdx.x * 256 + threadIdx.x;  // 8-elem index
  const uint4 raw = ((const uint4*)Z)[i8];
  const int c0 = (int)((i8 * 8) & 255);
  const float4 scA = *(const float4*)(scale + c0);
  const float4 scB = *(const float4*)(scale + c0 + 4);
  const float4 shA = *(const float4*)(shift + c0);
  const float4 shB = *(const float4*)(shift + c0 + 4);
  float4 oa, ob;
  oa.x = bfu2f((unsigned short)(raw.x & 0xffff)) * scA.x + shA.x;
  oa.y = bfu2f((unsigned short)(raw.x >> 16))    * scA.y + shA.y;
  oa.z = bfu2f((unsigned short)(raw.y & 0xffff)) * scA.z + shA.z;
  oa.w = bfu2f((unsigned short)(raw.y >> 16))    * scA.w + shA.w;
  ob.x = bfu2f((unsigned short)(raw.z & 0xffff)) * scB.x + shB.x;
  ob.y = bfu2f((unsigned short)(raw.z >> 16))    * scB.y + shB.y;
  ob.z = bfu2f((unsigned short)(raw.w & 0xffff)) * scB.z + shB.z;
  ob.w = bfu2f((unsigned short)(raw.w >> 16))    * scB.w + shB.w;
  ((float4*)(out))[i8 * 2]     = oa;
  ((float4*)(out))[i8 * 2 + 1] = ob;
}

// ---------------------------------------------------------------------------
extern "C" void kernel_launch(void* const* d_in, const int* in_sizes, int n_in,
                              void* d_out, int out_size, void* d_ws,
                              size_t ws_size, hipStream_t stream) {
  (void)in_sizes; (void)n_in; (void)out_size; (void)ws_size;
  const float* x        = (const float*)d_in[0];
  const float* pos      = (const float*)d_in[1];
  const float* x_skip   = (const float*)d_in[3];
  const float* pos_skip = (const float*)d_in[4];
  const float* W1  = (const float*)d_in[6];
  const float* b1  = (const float*)d_in[7];
  const float* g1  = (const float*)d_in[8];
  const float* be1 = (const float*)d_in[9];
  const float* W2  = (const float*)d_in[10];
  const float* b2  = (const float*)d_in[11];
  const float* g2  = (const float*)d_in[12];
  const float* be2 = (const float*)d_in[13];
  float* out = (float*)d_out;

  char* ws = (char*)d_ws;
  // Workspace layout (bytes); z2 aliases h0 (h0 dead after gemm1)
  __hip_bfloat16* h0  = (__hip_bfloat16*)(ws);                    // 50331648
  __hip_bfloat16* z2  = (__hip_bfloat16*)(ws);                    // 33554432
  __hip_bfloat16* W1t = (__hip_bfloat16*)(ws + 50331648);         // 196608
  __hip_bfloat16* z1  = (__hip_bfloat16*)(ws + 50528256);         // 33554432
  __hip_bfloat16* W2t = (__hip_bfloat16*)(ws + 84082688);         // 131072
  float* b2p    = (float*)(ws + 84213760);                        // 1024
  float* stats  = (float*)(ws + 84214784);                        // 4096
  float* scale1 = (float*)(ws + 84218880);                        // 4096
  float* shift1 = scale1 + 256;
  float* scale2 = scale1 + 512;
  float* shift2 = scale1 + 768;

  prep_w1_kernel<<<384, 256, 0, stream>>>(W1, W1t, stats);
  knn_interp_kernel<<<1024, 256, 0, stream>>>(x, pos, x_skip, pos_skip, h0);
  gemm_bias_relu<DIN><<<1024, 256, 0, stream>>>(h0, W1t, b1, z1,
                                                stats, stats + 256);
  bn_finalize_kernel<<<1, 256, 0, stream>>>(stats, stats + 256, g1, be1,
                                            scale1, shift1);
  prep_w2_kernel<<<256, 256, 0, stream>>>(W2, scale1, W2t);
  prep_b2_kernel<<<256, 64, 0, stream>>>(W2, shift1, b2, b2p);
  gemm_bias_relu<CHID><<<1024, 256, 0, stream>>>(z1, W2t, b2p, z2,
                                                 stats + 512, stats + 768);
  bn_finalize_kernel<<<1, 256, 0, stream>>>(stats + 512, stats + 768, g2, be2,
                                            scale2, shift2);
  bn_apply_kernel<<<8192, 256, 0, stream>>>(z2, scale2, shift2, out);
}

// Round 3
// 147.919 us; speedup vs baseline: 1.2411x; 1.0351x over previous
//
#include <hip/hip_runtime.h>
#include <hip/hip_bf16.h>

// Problem constants
#define NB    16
#define NC    1024
#define NF    4096
#define MROWS 65536      // NB*NF
#define CIN   256
#define CSK   128
#define DIN   384        // CIN + CSK
#define CHID  256
#define BN_EPS 1e-5f

typedef __attribute__((ext_vector_type(8))) short bf16x8;
typedef __attribute__((ext_vector_type(4))) float f32x4;

__device__ __forceinline__ unsigned short f2bfu(float f) {
  __hip_bfloat16 h = __float2bfloat16(f);
  return __builtin_bit_cast(unsigned short, h);
}
__device__ __forceinline__ float bfu2f(unsigned short u) {
  unsigned int w = ((unsigned int)u) << 16;
  return __builtin_bit_cast(float, w);
}

__device__ __forceinline__ void load_lds16(const void* g, void* lds) {
  __builtin_amdgcn_global_load_lds(
      (const __attribute__((address_space(1))) unsigned int*)g,
      (__attribute__((address_space(3))) unsigned int*)lds, 16, 0, 0);
}

// ---------------------------------------------------------------------------
// K1: kNN interpolate + concat -> h0 (MROWS x 384, bf16)
// 8 waves/block; each wave scans 128 candidates for 64 fine points
// (lane = point). In-register sorted top-3 via min/med3 + index cndmasks;
// strict-< insertion in ascending-index order == lax.top_k tie semantics.
// ---------------------------------------------------------------------------
__global__ __launch_bounds__(512) void knn_interp_kernel(
    const float* __restrict__ x,        // (NB*NC, 256)
    const float* __restrict__ pos,      // (NB*NC, 3)
    const float* __restrict__ x_skip,   // (NB*NF, 128)
    const float* __restrict__ pos_skip, // (NB*NF, 3)
    __hip_bfloat16* __restrict__ h0)    // (MROWS, 384)
{
  __shared__ float4 cpos[NC];          // 16 KB
  __shared__ float  md[8][64][3];      // 6 KB
  __shared__ int    mi[8][64][3];      // 6 KB
  __shared__ float  fw[64][3];
  __shared__ int    fi[64][3];

  const int tid = threadIdx.x, wid = tid >> 6, lane = tid & 63;
  const int f0 = blockIdx.x * 64;      // 64 fine points per block
  const int b  = f0 >> 12;             // batch (4096 fine pts / batch)

  const float* pb = pos + (size_t)b * NC * 3;
  for (int j = tid; j < NC; j += 512)
    cpos[j] = make_float4(pb[3 * j], pb[3 * j + 1], pb[3 * j + 2], 0.f);
  __syncthreads();

  const int f = f0 + lane;
  const float* pf = pos_skip + (size_t)f * 3;
  const float fx = pf[0], fy = pf[1], fz = pf[2];

  float b0 = 3.4e38f, b1 = 3.4e38f, b2v = 3.4e38f;
  int   i0 = 0, i1 = 0, i2 = 0;
  const int jbase = wid * 128;
#pragma unroll 4
  for (int jj = 0; jj < 128; ++jj) {
    const float4 c = cpos[jbase + jj];
    const float dx = __fsub_rn(fx, c.x);
    const float dy = __fsub_rn(fy, c.y);
    const float dz = __fsub_rn(fz, c.z);
    const float d2 = __fadd_rn(
        __fadd_rn(__fmul_rn(dx, dx), __fmul_rn(dy, dy)), __fmul_rn(dz, dz));
    const int j = jbase + jj;
    const bool c0 = d2 < b0, c1 = d2 < b1, c2 = d2 < b2v;
    const float nb1 = __builtin_amdgcn_fmed3f(d2, b0, b1);
    const float nb2 = __builtin_amdgcn_fmed3f(d2, b1, b2v);
    i2  = c1 ? i1 : (c2 ? j : i2);
    i1  = c0 ? i0 : (c1 ? j : i1);
    i0  = c0 ? j : i0;
    b2v = nb2;
    b1  = nb1;
    b0  = fminf(d2, b0);
  }
  md[wid][lane][0] = b0;  md[wid][lane][1] = b1;  md[wid][lane][2] = b2v;
  mi[wid][lane][0] = i0;  mi[wid][lane][1] = i1;  mi[wid][lane][2] = i2;
  __syncthreads();

  if (wid == 0) {
    // merge octants 1..7 in ascending order (their indices are all larger):
    // strict-< keeps the lower index on equal distance == top_k semantics.
#pragma unroll
    for (int q = 1; q < 8; ++q) {
#pragma unroll
      for (int e = 0; e < 3; ++e) {
        const float d = md[q][lane][e];
        const int   j = mi[q][lane][e];
        const bool c0 = d < b0, c1 = d < b1, c2 = d < b2v;
        const float nb1 = __builtin_amdgcn_fmed3f(d, b0, b1);
        const float nb2 = __builtin_amdgcn_fmed3f(d, b1, b2v);
        i2  = c1 ? i1 : (c2 ? j : i2);
        i1  = c0 ? i0 : (c1 ? j : i1);
        i0  = c0 ? j : i0;
        b2v = nb2;
        b1  = nb1;
        b0  = fminf(d, b0);
      }
    }
    float w0 = 1.f / fmaxf(b0, 1e-16f);
    float w1 = 1.f / fmaxf(b1, 1e-16f);
    float w2 = 1.f / fmaxf(b2v, 1e-16f);
    const float inv = 1.f / (w0 + w1 + w2);
    fw[lane][0] = w0 * inv; fw[lane][1] = w1 * inv; fw[lane][2] = w2 * inv;
    fi[lane][0] = i0; fi[lane][1] = i1; fi[lane][2] = i2;
  }
  __syncthreads();

  // gather: wave w handles points p = w*8 .. w*8+7 (coalesced per point)
  for (int pp = 0; pp < 8; ++pp) {
    const int p = wid * 8 + pp;
    const float w0 = fw[p][0], w1 = fw[p][1], w2 = fw[p][2];
    const int j0 = fi[p][0], j1 = fi[p][1], j2 = fi[p][2];
    const float4* r0 = (const float4*)(x + (size_t)(b * NC + j0) * CIN);
    const float4* r1 = (const float4*)(x + (size_t)(b * NC + j1) * CIN);
    const float4* r2 = (const float4*)(x + (size_t)(b * NC + j2) * CIN);
    const float4 a0 = r0[lane], a1 = r1[lane], a2 = r2[lane];
    float4 v;
    v.x = w0 * a0.x + w1 * a1.x + w2 * a2.x;
    v.y = w0 * a0.y + w1 * a1.y + w2 * a2.y;
    v.z = w0 * a0.z + w1 * a1.z + w2 * a2.z;
    v.w = w0 * a0.w + w1 * a1.w + w2 * a2.w;
    __hip_bfloat16* orow = h0 + (size_t)(f0 + p) * DIN;
    ushort4 o;
    o.x = f2bfu(v.x); o.y = f2bfu(v.y); o.z = f2bfu(v.z); o.w = f2bfu(v.w);
    ((ushort4*)orow)[lane] = o;
    // skip copy: 128 f32 -> bf16, 2 per lane
    const float2 s = ((const float2*)(x_skip + (size_t)(f0 + p) * CSK))[lane];
    const unsigned int packed =
        ((unsigned int)f2bfu(s.y) << 16) | (unsigned int)f2bfu(s.x);
    ((unsigned int*)(orow + CIN))[lane] = packed;
  }
}

// ---------------------------------------------------------------------------
// Weight prep: W1 transpose->bf16; block 0 also zeroes the stats buffer.
// ---------------------------------------------------------------------------
__global__ void prep_w1_kernel(const float* __restrict__ W1,
                               __hip_bfloat16* __restrict__ W1t,
                               float* __restrict__ stats) {
  int c = blockIdx.x, n = threadIdx.x;   // c in [0,384), n in [0,256)
  if (blockIdx.x == 0) {
    for (int k = threadIdx.x; k < 1024; k += 256) stats[k] = 0.f;
  }
  W1t[(size_t)n * DIN + c] = __float2bfloat16(W1[(size_t)c * CHID + n]);
}

// ---------------------------------------------------------------------------
// Fused BN1-finalize + W2 fold + b2 fold. Block n (0..255), thread c:
//   scale1[c]/shift1[c] from stats; W2t[n][c] = bf16(scale1[c]*W2[c][n]);
//   b2p[n] = b2[n] + sum_c shift1[c]*W2[c][n].
// ---------------------------------------------------------------------------
__global__ __launch_bounds__(256) void prep_w2b2_kernel(
    const float* __restrict__ W2, const float* __restrict__ stats,
    const float* __restrict__ g1, const float* __restrict__ be1,
    const float* __restrict__ b2, __hip_bfloat16* __restrict__ W2t,
    float* __restrict__ b2p) {
  const int n = blockIdx.x, c = threadIdx.x;
  const int wid = c >> 6, lane = c & 63;
  const float m = stats[c] * (1.f / MROWS);
  const float var = stats[256 + c] * (1.f / MROWS) - m * m;
  const float sc = g1[c] * rsqrtf(var + BN_EPS);
  const float sh = be1[c] - m * sc;
  const float w = W2[(size_t)c * CHID + n];
  W2t[(size_t)n * CHID + c] = __float2bfloat16(sc * w);
  float p = sh * w;
#pragma unroll
  for (int off = 32; off > 0; off >>= 1) p += __shfl_down(p, off);
  __shared__ float red4[4];
  if (lane == 0) red4[wid] = p;
  __syncthreads();
  if (c == 0) b2p[n] = red4[0] + red4[1] + red4[2] + red4[3] + b2[n];
}

// ---------------------------------------------------------------------------
// GEMM: Z(M x 256) = relu(A(M x KD) @ Bt^T + bias), bf16 out, fused
// per-column sum/sumsq accumulation for BatchNorm stats.
// 128x128 tile, BK=32, 4 waves (2x2 of 64x64), global_load_lds staging.
// ---------------------------------------------------------------------------
template<int KD>
__global__ __launch_bounds__(256) void gemm_bias_relu(
    const __hip_bfloat16* __restrict__ A,   // M x KD
    const __hip_bfloat16* __restrict__ Bt,  // 256 x KD
    const float* __restrict__ bias,         // 256
    __hip_bfloat16* __restrict__ out,       // M x 256 (bf16)
    float* __restrict__ gsum,               // 256
    float* __restrict__ gsq)                // 256
{
  __shared__ __hip_bfloat16 As[128 * 32];
  __shared__ __hip_bfloat16 Bs[128 * 32];
  __shared__ float ssum[128], ssq[128];
  const int tid = threadIdx.x;
  const int wid = tid >> 6, lane = tid & 63;
  const int bid = blockIdx.x;
  const int bm = bid >> 1, bn = bid & 1;
  const int wr = wid >> 1, wc = wid & 1;
  const int la = lane & 15, lk = lane >> 4;

  if (tid < 128) { ssum[tid] = 0.f; ssq[tid] = 0.f; }

  f32x4 acc[4][4] = {};

  const int rA = tid >> 2;            // 0..63
  const int c8 = (tid & 3) * 8;
  const __hip_bfloat16* gA0 = A + (size_t)(bm * 128 + rA) * KD + c8;
  const __hip_bfloat16* gA1 = gA0 + (size_t)64 * KD;
  const __hip_bfloat16* gB0 = Bt + (size_t)(bn * 128 + rA) * KD + c8;
  const __hip_bfloat16* gB1 = gB0 + (size_t)64 * KD;
  char* ldsA = (char*)As + wid * 1024;   // wave-uniform dest base
  char* ldsB = (char*)Bs + wid * 1024;

  const int nIter = KD / 32;
  for (int it = 0; it < nIter; ++it) {
    const int k0 = it * 32;
    load_lds16(gA0 + k0, ldsA);
    load_lds16(gA1 + k0, ldsA + 4096);
    load_lds16(gB0 + k0, ldsB);
    load_lds16(gB1 + k0, ldsB + 4096);
    __syncthreads();

    bf16x8 af[4], bfr[4];
#pragma unroll
    for (int m = 0; m < 4; ++m)
      af[m] = *(const bf16x8*)(As + (wr * 64 + m * 16 + la) * 32 + lk * 8);
#pragma unroll
    for (int n = 0; n < 4; ++n)
      bfr[n] = *(const bf16x8*)(Bs + (wc * 64 + n * 16 + la) * 32 + lk * 8);
#pragma unroll
    for (int m = 0; m < 4; ++m)
#pragma unroll
      for (int n = 0; n < 4; ++n)
        acc[m][n] = __builtin_amdgcn_mfma_f32_16x16x32_bf16(
            af[m], bfr[n], acc[m][n], 0, 0, 0);
    __syncthreads();
  }

  const int rowBase = bm * 128 + wr * 64 + lk * 4;
  const int lcolBase = wc * 64 + la;
#pragma unroll
  for (int n = 0; n < 4; ++n) {
    const int lcol = lcolBase + n * 16;
    const int col = bn * 128 + lcol;
    const float bs = bias[col];
    float ls = 0.f, ls2 = 0.f;
#pragma unroll
    for (int m = 0; m < 4; ++m) {
      const int row = rowBase + m * 16;
#pragma unroll
      for (int j = 0; j < 4; ++j) {
        float v = acc[m][n][j] + bs;
        v = fmaxf(v, 0.f);
        ls += v; ls2 += v * v;
        out[(size_t)(row + j) * 256 + col] = __float2bfloat16(v);
      }
    }
    atomicAdd(&ssum[lcol], ls);
    atomicAdd(&ssq[lcol], ls2);
  }
  __syncthreads();
  if (tid < 128) {
    atomicAdd(&gsum[bn * 128 + tid], ssum[tid]);
    atomicAdd(&gsq[bn * 128 + tid], ssq[tid]);
  }
}

// ---------------------------------------------------------------------------
// bn apply (with inlined BN2 finalize): read bf16 z2, write f32 out.
// ---------------------------------------------------------------------------
__global__ __launch_bounds__(256) void bn_apply_kernel(
    const __hip_bfloat16* __restrict__ Z, const float* __restrict__ stats,
    const float* __restrict__ g2, const float* __restrict__ be2,
    float* __restrict__ out) {
  __shared__ float ssc[256], ssh[256];
  const int t = threadIdx.x;
  {
    const float m = stats[t] * (1.f / MROWS);
    const float var = stats[256 + t] * (1.f / MROWS) - m * m;
    const float sc = g2[t] * rsqrtf(var + BN_EPS);
    ssc[t] = sc;
    ssh[t] = be2[t] - m * sc;
  }
  __syncthreads();
  const size_t i8 = (size_t)blockIdx.x * 256 + t;  // 8-elem index
  const uint4 raw = ((const uint4*)Z)[i8];
  const int c0 = (int)((i8 * 8) & 255);
  const float4 scA = *(const float4*)(ssc + c0);
  const float4 scB = *(const float4*)(ssc + c0 + 4);
  const float4 shA = *(const float4*)(ssh + c0);
  const float4 shB = *(const float4*)(ssh + c0 + 4);
  float4 oa, ob;
  oa.x = bfu2f((unsigned short)(raw.x & 0xffff)) * scA.x + shA.x;
  oa.y = bfu2f((unsigned short)(raw.x >> 16))    * scA.y + shA.y;
  oa.z = bfu2f((unsigned short)(raw.y & 0xffff)) * scA.z + shA.z;
  oa.w = bfu2f((unsigned short)(raw.y >> 16))    * scA.w + shA.w;
  ob.x = bfu2f((unsigned short)(raw.z & 0xffff)) * scB.x + shB.x;
  ob.y = bfu2f((unsigned short)(raw.z >> 16))    * scB.y + shB.y;
  ob.z = bfu2f((unsigned short)(raw.w & 0xffff)) * scB.z + shB.z;
  ob.w = bfu2f((unsigned short)(raw.w >> 16))    * scB.w + shB.w;
  ((float4*)(out))[i8 * 2]     = oa;
  ((float4*)(out))[i8 * 2 + 1] = ob;
}

// ---------------------------------------------------------------------------
extern "C" void kernel_launch(void* const* d_in, const int* in_sizes, int n_in,
                              void* d_out, int out_size, void* d_ws,
                              size_t ws_size, hipStream_t stream) {
  (void)in_sizes; (void)n_in; (void)out_size; (void)ws_size;
  const float* x        = (const float*)d_in[0];
  const float* pos      = (const float*)d_in[1];
  const float* x_skip   = (const float*)d_in[3];
  const float* pos_skip = (const float*)d_in[4];
  const float* W1  = (const float*)d_in[6];
  const float* b1  = (const float*)d_in[7];
  const float* g1  = (const float*)d_in[8];
  const float* be1 = (const float*)d_in[9];
  const float* W2  = (const float*)d_in[10];
  const float* b2  = (const float*)d_in[11];
  const float* g2  = (const float*)d_in[12];
  const float* be2 = (const float*)d_in[13];
  float* out = (float*)d_out;

  char* ws = (char*)d_ws;
  // Workspace layout (bytes); z2 aliases h0 (h0 dead after gemm1)
  __hip_bfloat16* h0  = (__hip_bfloat16*)(ws);                    // 50331648
  __hip_bfloat16* z2  = (__hip_bfloat16*)(ws);                    // 33554432
  __hip_bfloat16* W1t = (__hip_bfloat16*)(ws + 50331648);         // 196608
  __hip_bfloat16* z1  = (__hip_bfloat16*)(ws + 50528256);         // 33554432
  __hip_bfloat16* W2t = (__hip_bfloat16*)(ws + 84082688);         // 131072
  float* b2p    = (float*)(ws + 84213760);                        // 1024
  float* stats  = (float*)(ws + 84214784);                        // 4096

  prep_w1_kernel<<<384, 256, 0, stream>>>(W1, W1t, stats);
  knn_interp_kernel<<<1024, 512, 0, stream>>>(x, pos, x_skip, pos_skip, h0);
  gemm_bias_relu<DIN><<<1024, 256, 0, stream>>>(h0, W1t, b1, z1,
                                                stats, stats + 256);
  prep_w2b2_kernel<<<256, 256, 0, stream>>>(W2, stats, g1, be1, b2, W2t, b2p);
  gemm_bias_relu<CHID><<<1024, 256, 0, stream>>>(z1, W2t, b2p, z2,
                                                 stats + 512, stats + 768);
  bn_apply_kernel<<<8192, 256, 0, stream>>>(z2, stats + 512, g2, be2, out);
}

// Round 4
// 142.947 us; speedup vs baseline: 1.2843x; 1.0348x over previous
//
#include <hip/hip_runtime.h>
#include <hip/hip_bf16.h>

// Problem constants
#define NB    16
#define NC    1024
#define NF    4096
#define MROWS 65536      // NB*NF
#define CIN   256
#define CSK   128
#define DIN   384        // CIN + CSK
#define CHID  256
#define BN_EPS 1e-5f

typedef __attribute__((ext_vector_type(8))) short bf16x8;
typedef __attribute__((ext_vector_type(4))) float f32x4;

__device__ __forceinline__ unsigned short f2bfu(float f) {
  __hip_bfloat16 h = __float2bfloat16(f);
  return __builtin_bit_cast(unsigned short, h);
}
__device__ __forceinline__ float bfu2f(unsigned short u) {
  unsigned int w = ((unsigned int)u) << 16;
  return __builtin_bit_cast(float, w);
}

__device__ __forceinline__ void load_lds16(const void* g, void* lds) {
  __builtin_amdgcn_global_load_lds(
      (const __attribute__((address_space(1))) unsigned int*)g,
      (__attribute__((address_space(3))) unsigned int*)lds, 16, 0, 0);
}

// ---------------------------------------------------------------------------
// K1: kNN interpolate + concat -> h0 (MROWS x 384, bf16)
// Blocks [0,1024): 8 waves/block; each wave scans 128 candidates for 64 fine
// points (lane = point). In-register sorted top-3 via min/med3 + index
// cndmasks; strict-< insertion in ascending-index order == lax.top_k tie
// semantics. Blocks [1024,1408): W1 transpose->bf16 prep + stats zeroing.
// ---------------------------------------------------------------------------
__global__ __launch_bounds__(512) void knn_interp_kernel(
    const float* __restrict__ x,        // (NB*NC, 256)
    const float* __restrict__ pos,      // (NB*NC, 3)
    const float* __restrict__ x_skip,   // (NB*NF, 128)
    const float* __restrict__ pos_skip, // (NB*NF, 3)
    __hip_bfloat16* __restrict__ h0,    // (MROWS, 384)
    const float* __restrict__ W1,
    __hip_bfloat16* __restrict__ W1t,
    float* __restrict__ stats)
{
  const int tid = threadIdx.x, wid = tid >> 6, lane = tid & 63;

  if (blockIdx.x >= 1024) {            // prep-W1 role (block-uniform branch)
    const int c = blockIdx.x - 1024;   // 0..383
    if (c == 0 && tid < 256) {
      for (int k = tid; k < 1024; k += 256) stats[k] = 0.f;
    }
    if (tid < 256)
      W1t[(size_t)tid * DIN + c] = __float2bfloat16(W1[(size_t)c * CHID + tid]);
    return;
  }

  __shared__ float4 cpos[NC];          // 16 KB
  __shared__ float  md[8][64][3];      // 6 KB
  __shared__ int    mi[8][64][3];      // 6 KB
  __shared__ float  fw[64][3];
  __shared__ int    fi[64][3];

  const int f0 = blockIdx.x * 64;      // 64 fine points per block
  const int b  = f0 >> 12;             // batch (4096 fine pts / batch)

  const float* pb = pos + (size_t)b * NC * 3;
  for (int j = tid; j < NC; j += 512)
    cpos[j] = make_float4(pb[3 * j], pb[3 * j + 1], pb[3 * j + 2], 0.f);
  __syncthreads();

  const int f = f0 + lane;
  const float* pf = pos_skip + (size_t)f * 3;
  const float fx = pf[0], fy = pf[1], fz = pf[2];

  float b0 = 3.4e38f, b1 = 3.4e38f, b2v = 3.4e38f;
  int   i0 = 0, i1 = 0, i2 = 0;
  const int jbase = wid * 128;
#pragma unroll 8
  for (int jj = 0; jj < 128; ++jj) {
    const float4 c = cpos[jbase + jj];
    const float dx = __fsub_rn(fx, c.x);
    const float dy = __fsub_rn(fy, c.y);
    const float dz = __fsub_rn(fz, c.z);
    const float d2 = __fadd_rn(
        __fadd_rn(__fmul_rn(dx, dx), __fmul_rn(dy, dy)), __fmul_rn(dz, dz));
    const int j = jbase + jj;
    const bool c0 = d2 < b0, c1 = d2 < b1, c2 = d2 < b2v;
    const float nb1 = __builtin_amdgcn_fmed3f(d2, b0, b1);
    const float nb2 = __builtin_amdgcn_fmed3f(d2, b1, b2v);
    i2  = c1 ? i1 : (c2 ? j : i2);
    i1  = c0 ? i0 : (c1 ? j : i1);
    i0  = c0 ? j : i0;
    b2v = nb2;
    b1  = nb1;
    b0  = fminf(d2, b0);
  }
  md[wid][lane][0] = b0;  md[wid][lane][1] = b1;  md[wid][lane][2] = b2v;
  mi[wid][lane][0] = i0;  mi[wid][lane][1] = i1;  mi[wid][lane][2] = i2;
  __syncthreads();

  if (wid == 0) {
    // merge octants 1..7 in ascending order (their indices are all larger):
    // strict-< keeps the lower index on equal distance == top_k semantics.
#pragma unroll
    for (int q = 1; q < 8; ++q) {
#pragma unroll
      for (int e = 0; e < 3; ++e) {
        const float d = md[q][lane][e];
        const int   j = mi[q][lane][e];
        const bool c0 = d < b0, c1 = d < b1, c2 = d < b2v;
        const float nb1 = __builtin_amdgcn_fmed3f(d, b0, b1);
        const float nb2 = __builtin_amdgcn_fmed3f(d, b1, b2v);
        i2  = c1 ? i1 : (c2 ? j : i2);
        i1  = c0 ? i0 : (c1 ? j : i1);
        i0  = c0 ? j : i0;
        b2v = nb2;
        b1  = nb1;
        b0  = fminf(d, b0);
      }
    }
    float w0 = 1.f / fmaxf(b0, 1e-16f);
    float w1 = 1.f / fmaxf(b1, 1e-16f);
    float w2 = 1.f / fmaxf(b2v, 1e-16f);
    const float inv = 1.f / (w0 + w1 + w2);
    fw[lane][0] = w0 * inv; fw[lane][1] = w1 * inv; fw[lane][2] = w2 * inv;
    fi[lane][0] = i0; fi[lane][1] = i1; fi[lane][2] = i2;
  }
  __syncthreads();

  // gather: wave w handles points p = w*8 .. w*8+7 (coalesced per point)
  for (int pp = 0; pp < 8; ++pp) {
    const int p = wid * 8 + pp;
    const float w0 = fw[p][0], w1 = fw[p][1], w2 = fw[p][2];
    const int j0 = fi[p][0], j1 = fi[p][1], j2 = fi[p][2];
    const float4* r0 = (const float4*)(x + (size_t)(b * NC + j0) * CIN);
    const float4* r1 = (const float4*)(x + (size_t)(b * NC + j1) * CIN);
    const float4* r2 = (const float4*)(x + (size_t)(b * NC + j2) * CIN);
    const float4 a0 = r0[lane], a1 = r1[lane], a2 = r2[lane];
    float4 v;
    v.x = w0 * a0.x + w1 * a1.x + w2 * a2.x;
    v.y = w0 * a0.y + w1 * a1.y + w2 * a2.y;
    v.z = w0 * a0.z + w1 * a1.z + w2 * a2.z;
    v.w = w0 * a0.w + w1 * a1.w + w2 * a2.w;
    __hip_bfloat16* orow = h0 + (size_t)(f0 + p) * DIN;
    ushort4 o;
    o.x = f2bfu(v.x); o.y = f2bfu(v.y); o.z = f2bfu(v.z); o.w = f2bfu(v.w);
    ((ushort4*)orow)[lane] = o;
    // skip copy: 128 f32 -> bf16, 2 per lane
    const float2 s = ((const float2*)(x_skip + (size_t)(f0 + p) * CSK))[lane];
    const unsigned int packed =
        ((unsigned int)f2bfu(s.y) << 16) | (unsigned int)f2bfu(s.x);
    ((unsigned int*)(orow + CIN))[lane] = packed;
  }
}

// ---------------------------------------------------------------------------
// Fused BN1-finalize + W2 fold + b2 fold. Block n (0..255), thread c:
//   scale1[c]/shift1[c] from stats; W2t[n][c] = bf16(scale1[c]*W2[c][n]);
//   b2p[n] = b2[n] + sum_c shift1[c]*W2[c][n].
// ---------------------------------------------------------------------------
__global__ __launch_bounds__(256) void prep_w2b2_kernel(
    const float* __restrict__ W2, const float* __restrict__ stats,
    const float* __restrict__ g1, const float* __restrict__ be1,
    const float* __restrict__ b2, __hip_bfloat16* __restrict__ W2t,
    float* __restrict__ b2p) {
  const int n = blockIdx.x, c = threadIdx.x;
  const int wid = c >> 6, lane = c & 63;
  const float m = stats[c] * (1.f / MROWS);
  const float var = stats[256 + c] * (1.f / MROWS) - m * m;
  const float sc = g1[c] * rsqrtf(var + BN_EPS);
  const float sh = be1[c] - m * sc;
  const float w = W2[(size_t)c * CHID + n];
  W2t[(size_t)n * CHID + c] = __float2bfloat16(sc * w);
  float p = sh * w;
#pragma unroll
  for (int off = 32; off > 0; off >>= 1) p += __shfl_down(p, off);
  __shared__ float red4[4];
  if (lane == 0) red4[wid] = p;
  __syncthreads();
  if (c == 0) b2p[n] = red4[0] + red4[1] + red4[2] + red4[3] + b2[n];
}

// ---------------------------------------------------------------------------
// GEMM: Z(M x 256) = relu(A(M x KD) @ Bt^T + bias), bf16 out, fused
// per-column sum/sumsq accumulation for BatchNorm stats.
// 128x256 tile (full N -> A read ONCE), BK=32, 8 waves (2x4 of 64x64),
// global_load_lds staging (A: 1 inst/thread, B: 2).
// ---------------------------------------------------------------------------
template<int KD>
__global__ __launch_bounds__(512) void gemm_bias_relu(
    const __hip_bfloat16* __restrict__ A,   // M x KD
    const __hip_bfloat16* __restrict__ Bt,  // 256 x KD
    const float* __restrict__ bias,         // 256
    __hip_bfloat16* __restrict__ out,       // M x 256 (bf16)
    float* __restrict__ gsum,               // 256
    float* __restrict__ gsq)                // 256
{
  __shared__ __hip_bfloat16 As[128 * 32];   // 8 KB
  __shared__ __hip_bfloat16 Bs[256 * 32];   // 16 KB
  __shared__ float ssum[256], ssq[256];
  const int tid = threadIdx.x;
  const int wid = tid >> 6, lane = tid & 63;
  const int bm = blockIdx.x;                // 512 blocks, M/128
  const int wr = wid >> 2, wc = wid & 3;    // 2 x 4 waves of 64x64
  const int la = lane & 15, lk = lane >> 4;

  if (tid < 256) { ssum[tid] = 0.f; ssq[tid] = 0.f; }

  f32x4 acc[4][4] = {};

  const int rA = tid >> 2;            // 0..127
  const int c8 = (tid & 3) * 8;
  const __hip_bfloat16* gA  = A  + (size_t)(bm * 128 + rA) * KD + c8;
  const __hip_bfloat16* gB0 = Bt + (size_t)rA * KD + c8;
  const __hip_bfloat16* gB1 = Bt + (size_t)(128 + rA) * KD + c8;
  char* ldsA  = (char*)As + wid * 1024;     // wave-uniform dest bases
  char* ldsB0 = (char*)Bs + wid * 1024;
  char* ldsB1 = (char*)Bs + 8192 + wid * 1024;

  const int nIter = KD / 32;
  for (int it = 0; it < nIter; ++it) {
    const int k0 = it * 32;
    load_lds16(gA  + k0, ldsA);
    load_lds16(gB0 + k0, ldsB0);
    load_lds16(gB1 + k0, ldsB1);
    __syncthreads();

    bf16x8 af[4], bfr[4];
#pragma unroll
    for (int m = 0; m < 4; ++m)
      af[m] = *(const bf16x8*)(As + (wr * 64 + m * 16 + la) * 32 + lk * 8);
#pragma unroll
    for (int n = 0; n < 4; ++n)
      bfr[n] = *(const bf16x8*)(Bs + (wc * 64 + n * 16 + la) * 32 + lk * 8);
#pragma unroll
    for (int m = 0; m < 4; ++m)
#pragma unroll
      for (int n = 0; n < 4; ++n)
        acc[m][n] = __builtin_amdgcn_mfma_f32_16x16x32_bf16(
            af[m], bfr[n], acc[m][n], 0, 0, 0);
    __syncthreads();
  }

  const int rowBase = bm * 128 + wr * 64 + lk * 4;
#pragma unroll
  for (int n = 0; n < 4; ++n) {
    const int col = wc * 64 + n * 16 + la;   // 0..255 (full N in-block)
    const float bs = bias[col];
    float ls = 0.f, ls2 = 0.f;
#pragma unroll
    for (int m = 0; m < 4; ++m) {
      const int row = rowBase + m * 16;
#pragma unroll
      for (int j = 0; j < 4; ++j) {
        float v = acc[m][n][j] + bs;
        v = fmaxf(v, 0.f);
        ls += v; ls2 += v * v;
        out[(size_t)(row + j) * 256 + col] = __float2bfloat16(v);
      }
    }
    atomicAdd(&ssum[col], ls);
    atomicAdd(&ssq[col], ls2);
  }
  __syncthreads();
  if (tid < 256) {
    atomicAdd(&gsum[tid], ssum[tid]);
    atomicAdd(&gsq[tid], ssq[tid]);
  }
}

// ---------------------------------------------------------------------------
// bn apply (with inlined BN2 finalize): read bf16 z2, write f32 out.
// ---------------------------------------------------------------------------
__global__ __launch_bounds__(256) void bn_apply_kernel(
    const __hip_bfloat16* __restrict__ Z, const float* __restrict__ stats,
    const float* __restrict__ g2, const float* __restrict__ be2,
    float* __restrict__ out) {
  __shared__ float ssc[256], ssh[256];
  const int t = threadIdx.x;
  {
    const float m = stats[t] * (1.f / MROWS);
    const float var = stats[256 + t] * (1.f / MROWS) - m * m;
    const float sc = g2[t] * rsqrtf(var + BN_EPS);
    ssc[t] = sc;
    ssh[t] = be2[t] - m * sc;
  }
  __syncthreads();
  const size_t i8 = (size_t)blockIdx.x * 256 + t;  // 8-elem index
  const uint4 raw = ((const uint4*)Z)[i8];
  const int c0 = (int)((i8 * 8) & 255);
  const float4 scA = *(const float4*)(ssc + c0);
  const float4 scB = *(const float4*)(ssc + c0 + 4);
  const float4 shA = *(const float4*)(ssh + c0);
  const float4 shB = *(const float4*)(ssh + c0 + 4);
  float4 oa, ob;
  oa.x = bfu2f((unsigned short)(raw.x & 0xffff)) * scA.x + shA.x;
  oa.y = bfu2f((unsigned short)(raw.x >> 16))    * scA.y + shA.y;
  oa.z = bfu2f((unsigned short)(raw.y & 0xffff)) * scA.z + shA.z;
  oa.w = bfu2f((unsigned short)(raw.y >> 16))    * scA.w + shA.w;
  ob.x = bfu2f((unsigned short)(raw.z & 0xffff)) * scB.x + shB.x;
  ob.y = bfu2f((unsigned short)(raw.z >> 16))    * scB.y + shB.y;
  ob.z = bfu2f((unsigned short)(raw.w & 0xffff)) * scB.z + shB.z;
  ob.w = bfu2f((unsigned short)(raw.w >> 16))    * scB.w + shB.w;
  ((float4*)(out))[i8 * 2]     = oa;
  ((float4*)(out))[i8 * 2 + 1] = ob;
}

// ---------------------------------------------------------------------------
extern "C" void kernel_launch(void* const* d_in, const int* in_sizes, int n_in,
                              void* d_out, int out_size, void* d_ws,
                              size_t ws_size, hipStream_t stream) {
  (void)in_sizes; (void)n_in; (void)out_size; (void)ws_size;
  const float* x        = (const float*)d_in[0];
  const float* pos      = (const float*)d_in[1];
  const float* x_skip   = (const float*)d_in[3];
  const float* pos_skip = (const float*)d_in[4];
  const float* W1  = (const float*)d_in[6];
  const float* b1  = (const float*)d_in[7];
  const float* g1  = (const float*)d_in[8];
  const float* be1 = (const float*)d_in[9];
  const float* W2  = (const float*)d_in[10];
  const float* b2  = (const float*)d_in[11];
  const float* g2  = (const float*)d_in[12];
  const float* be2 = (const float*)d_in[13];
  float* out = (float*)d_out;

  char* ws = (char*)d_ws;
  // Workspace layout (bytes); z2 aliases h0 (h0 dead after gemm1)
  __hip_bfloat16* h0  = (__hip_bfloat16*)(ws);                    // 50331648
  __hip_bfloat16* z2  = (__hip_bfloat16*)(ws);                    // 33554432
  __hip_bfloat16* W1t = (__hip_bfloat16*)(ws + 50331648);         // 196608
  __hip_bfloat16* z1  = (__hip_bfloat16*)(ws + 50528256);         // 33554432
  __hip_bfloat16* W2t = (__hip_bfloat16*)(ws + 84082688);         // 131072
  float* b2p    = (float*)(ws + 84213760);                        // 1024
  float* stats  = (float*)(ws + 84214784);                        // 4096

  knn_interp_kernel<<<1408, 512, 0, stream>>>(x, pos, x_skip, pos_skip, h0,
                                              W1, W1t, stats);
  gemm_bias_relu<DIN><<<512, 512, 0, stream>>>(h0, W1t, b1, z1,
                                               stats, stats + 256);
  prep_w2b2_kernel<<<256, 256, 0, stream>>>(W2, stats, g1, be1, b2, W2t, b2p);
  gemm_bias_relu<CHID><<<512, 512, 0, stream>>>(z1, W2t, b2p, z2,
                                                stats + 512, stats + 768);
  bn_apply_kernel<<<8192, 256, 0, stream>>>(z2, stats + 512, g2, be2, out);
}

// Round 6
// 136.881 us; speedup vs baseline: 1.3412x; 1.0443x over previous
//
#include <hip/hip_runtime.h>
#include <hip/hip_bf16.h>

// Problem constants
#define NB    16
#define NC    1024
#define NF    4096
#define MROWS 65536      // NB*NF
#define CIN   256
#define CSK   128
#define DIN   384        // CIN + CSK
#define CHID  256
#define BN_EPS 1e-5f

typedef __attribute__((ext_vector_type(8))) short bf16x8;
typedef __attribute__((ext_vector_type(4))) float f32x4;
typedef __attribute__((ext_vector_type(2))) float f32x2;

__device__ __forceinline__ unsigned short f2bfu(float f) {
  __hip_bfloat16 h = __float2bfloat16(f);
  return __builtin_bit_cast(unsigned short, h);
}
__device__ __forceinline__ float bfu2f(unsigned short u) {
  unsigned int w = ((unsigned int)u) << 16;
  return __builtin_bit_cast(float, w);
}

__device__ __forceinline__ void load_lds16(const void* g, void* lds) {
  __builtin_amdgcn_global_load_lds(
      (const __attribute__((address_space(1))) unsigned int*)g,
      (__attribute__((address_space(3))) unsigned int*)lds, 16, 0, 0);
}

// sorted top-3 insert, strict-< (== lax.top_k tie rule: lower index wins)
__device__ __forceinline__ void ins3(float d2, int j, float& b0, float& b1,
                                     float& b2v, int& i0, int& i1, int& i2) {
  const bool c0 = d2 < b0, c1 = d2 < b1, c2 = d2 < b2v;
  const float nb1 = __builtin_amdgcn_fmed3f(d2, b0, b1);
  const float nb2 = __builtin_amdgcn_fmed3f(d2, b1, b2v);
  i2  = c1 ? i1 : (c2 ? j : i2);
  i1  = c0 ? i0 : (c1 ? j : i1);
  i0  = c0 ? j : i0;
  b2v = nb2;
  b1  = nb1;
  b0  = fminf(d2, b0);
}

// ---------------------------------------------------------------------------
// K1: kNN interpolate + concat -> h0 (MROWS x 384, bf16)
// Blocks [0,1024): 8 waves/block; each wave scans 64 candidate PAIRS using
// packed-f32 (v_pk_*) distance math on negated positions (bit-exact vs
// reference: fx + (-cx) == fx - cx; contract(off) keeps mul/add unfused).
// Blocks [1024,1408): W1 transpose->bf16 prep + stats zeroing.
// ---------------------------------------------------------------------------
__global__ __launch_bounds__(512) void knn_interp_kernel(
    const float* __restrict__ x,        // (NB*NC, 256)
    const float* __restrict__ pos,      // (NB*NC, 3)
    const float* __restrict__ x_skip,   // (NB*NF, 128)
    const float* __restrict__ pos_skip, // (NB*NF, 3)
    __hip_bfloat16* __restrict__ h0,    // (MROWS, 384)
    const float* __restrict__ W1,
    __hip_bfloat16* __restrict__ W1t,
    float* __restrict__ stats)
{
  const int tid = threadIdx.x, wid = tid >> 6, lane = tid & 63;

  if (blockIdx.x >= 1024) {            // prep-W1 role (block-uniform branch)
    const int c = blockIdx.x - 1024;   // 0..383
    if (c == 0 && tid < 256) {
      for (int k = tid; k < 1024; k += 256) stats[k] = 0.f;
    }
    if (tid < 256)
      W1t[(size_t)tid * DIN + c] = __float2bfloat16(W1[(size_t)c * CHID + tid]);
    return;
  }

  __shared__ f32x4 nxy[512];           // (-x0,-x1,-y0,-y1) per candidate pair
  __shared__ f32x2 nz[512];            // (-z0,-z1)
  __shared__ float  md[8][64][3];
  __shared__ int    mi[8][64][3];
  __shared__ float  fw[64][3];
  __shared__ int    fi[64][3];

  const int f0 = blockIdx.x * 64;      // 64 fine points per block
  const int b  = f0 >> 12;             // batch (4096 fine pts / batch)

  const float* pb = pos + (size_t)b * NC * 3;
  for (int j = tid; j < 512; j += 512) {     // one pair per thread, coalesced
    const float* p = pb + 6 * j;
    nxy[j] = (f32x4){-p[0], -p[3], -p[1], -p[4]};
    nz[j]  = (f32x2){-p[2], -p[5]};
  }
  __syncthreads();

  const int f = f0 + lane;
  const float* pf = pos_skip + (size_t)f * 3;
  const float fx = pf[0], fy = pf[1], fz = pf[2];
  const f32x4 fxxyy = (f32x4){fx, fx, fy, fy};
  const f32x2 fzz = (f32x2){fz, fz};

  float b0 = 3.4e38f, b1 = 3.4e38f, b2v = 3.4e38f;
  int   i0 = 0, i1 = 0, i2 = 0;
  const int pbase = wid * 64;          // 64 pairs (128 candidates) per wave
#pragma unroll 4
  for (int p = 0; p < 64; ++p) {
    const f32x4 cxy = nxy[pbase + p];
    const f32x2 cz  = nz[pbase + p];
    f32x2 d2;
    {
#pragma clang fp contract(off)
      const f32x4 dxy = fxxyy + cxy;        // (dx0,dx1,dy0,dy1)
      const f32x4 sq  = dxy * dxy;
      const f32x2 sxy = (f32x2){sq[0], sq[1]} + (f32x2){sq[2], sq[3]};
      const f32x2 dz  = fzz + cz;
      d2 = sxy + dz * dz;                   // (dx^2+dy^2)+dz^2, rn each step
    }
    const int j = 2 * (pbase + p);
    ins3(d2[0], j,     b0, b1, b2v, i0, i1, i2);
    ins3(d2[1], j + 1, b0, b1, b2v, i0, i1, i2);
  }
  md[wid][lane][0] = b0;  md[wid][lane][1] = b1;  md[wid][lane][2] = b2v;
  mi[wid][lane][0] = i0;  mi[wid][lane][1] = i1;  mi[wid][lane][2] = i2;
  __syncthreads();

  if (wid == 0) {
    // merge octants 1..7 in ascending order (their indices are all larger):
#pragma unroll
    for (int q = 1; q < 8; ++q)
#pragma unroll
      for (int e = 0; e < 3; ++e)
        ins3(md[q][lane][e], mi[q][lane][e], b0, b1, b2v, i0, i1, i2);

    float w0 = 1.f / fmaxf(b0, 1e-16f);
    float w1 = 1.f / fmaxf(b1, 1e-16f);
    float w2 = 1.f / fmaxf(b2v, 1e-16f);
    const float inv = 1.f / (w0 + w1 + w2);
    fw[lane][0] = w0 * inv; fw[lane][1] = w1 * inv; fw[lane][2] = w2 * inv;
    fi[lane][0] = i0; fi[lane][1] = i1; fi[lane][2] = i2;
  }
  __syncthreads();

  // gather: wave w handles points p = w*8 .. w*8+7 (coalesced per point)
  for (int pp = 0; pp < 8; ++pp) {
    const int p = wid * 8 + pp;
    const float w0 = fw[p][0], w1 = fw[p][1], w2 = fw[p][2];
    const int j0 = fi[p][0], j1 = fi[p][1], j2 = fi[p][2];
    const float4* r0 = (const float4*)(x + (size_t)(b * NC + j0) * CIN);
    const float4* r1 = (const float4*)(x + (size_t)(b * NC + j1) * CIN);
    const float4* r2 = (const float4*)(x + (size_t)(b * NC + j2) * CIN);
    const float4 a0 = r0[lane], a1 = r1[lane], a2 = r2[lane];
    float4 v;
    v.x = w0 * a0.x + w1 * a1.x + w2 * a2.x;
    v.y = w0 * a0.y + w1 * a1.y + w2 * a2.y;
    v.z = w0 * a0.z + w1 * a1.z + w2 * a2.z;
    v.w = w0 * a0.w + w1 * a1.w + w2 * a2.w;
    __hip_bfloat16* orow = h0 + (size_t)(f0 + p) * DIN;
    ushort4 o;
    o.x = f2bfu(v.x); o.y = f2bfu(v.y); o.z = f2bfu(v.z); o.w = f2bfu(v.w);
    ((ushort4*)orow)[lane] = o;
    const float2 s = ((const float2*)(x_skip + (size_t)(f0 + p) * CSK))[lane];
    const unsigned int packed =
        ((unsigned int)f2bfu(s.y) << 16) | (unsigned int)f2bfu(s.x);
    ((unsigned int*)(orow + CIN))[lane] = packed;
  }
}

// ---------------------------------------------------------------------------
// Fused BN1-finalize + W2 fold + b2 fold.
// ---------------------------------------------------------------------------
__global__ __launch_bounds__(256) void prep_w2b2_kernel(
    const float* __restrict__ W2, const float* __restrict__ stats,
    const float* __restrict__ g1, const float* __restrict__ be1,
    const float* __restrict__ b2, __hip_bfloat16* __restrict__ W2t,
    float* __restrict__ b2p) {
  const int n = blockIdx.x, c = threadIdx.x;
  const int wid = c >> 6, lane = c & 63;
  const float m = stats[c] * (1.f / MROWS);
  const float var = stats[256 + c] * (1.f / MROWS) - m * m;
  const float sc = g1[c] * rsqrtf(var + BN_EPS);
  const float sh = be1[c] - m * sc;
  const float w = W2[(size_t)c * CHID + n];
  W2t[(size_t)n * CHID + c] = __float2bfloat16(sc * w);
  float p = sh * w;
#pragma unroll
  for (int off = 32; off > 0; off >>= 1) p += __shfl_down(p, off);
  __shared__ float red4[4];
  if (lane == 0) red4[wid] = p;
  __syncthreads();
  if (c == 0) b2p[n] = red4[0] + red4[1] + red4[2] + red4[3] + b2[n];
}

// ---------------------------------------------------------------------------
// GEMM: Z(M x 256) = relu(A(M x KD) @ Bt^T + bias), bf16 out, fused
// per-column sum/sumsq for BN. 128x256 tile (full N -> A read once), BK=32,
// 8 waves (2x4 of 64x64). 2-PHASE PREFETCH: double-buffered LDS; next tile's
// global_load_lds issued BEFORE current tile's ds_read+MFMA; one barrier/iter
// (its vmcnt(0)+lgkmcnt(0) drain covers both the prefetch and the reads).
// ---------------------------------------------------------------------------
template<int KD>
__global__ __launch_bounds__(512) void gemm_bias_relu(
    const __hip_bfloat16* __restrict__ A,   // M x KD
    const __hip_bfloat16* __restrict__ Bt,  // 256 x KD
    const float* __restrict__ bias,         // 256
    __hip_bfloat16* __restrict__ out,       // M x 256 (bf16)
    float* __restrict__ gsum,               // 256
    float* __restrict__ gsq)                // 256
{
  __shared__ __hip_bfloat16 As[2 * 128 * 32];   // 16 KB (2 bufs)
  __shared__ __hip_bfloat16 Bs[2 * 256 * 32];   // 32 KB (2 bufs)
  __shared__ float ssum[256], ssq[256];
  const int tid = threadIdx.x;
  const int wid = tid >> 6, lane = tid & 63;
  const int bm = blockIdx.x;                // 512 blocks, M/128
  const int wr = wid >> 2, wc = wid & 3;    // 2 x 4 waves of 64x64
  const int la = lane & 15, lk = lane >> 4;

  if (tid < 256) { ssum[tid] = 0.f; ssq[tid] = 0.f; }

  f32x4 acc[4][4] = {};

  const int rA = tid >> 2;            // 0..127
  const int c8 = (tid & 3) * 8;
  const __hip_bfloat16* gA  = A  + (size_t)(bm * 128 + rA) * KD + c8;
  const __hip_bfloat16* gB0 = Bt + (size_t)rA * KD + c8;
  const __hip_bfloat16* gB1 = Bt + (size_t)(128 + rA) * KD + c8;
  char* ldsA  = (char*)As + wid * 1024;     // wave-uniform dest bases
  char* ldsB0 = (char*)Bs + wid * 1024;

  // prologue: stage tile 0 into buffer 0
  load_lds16(gA,       ldsA);
  load_lds16(gB0,      ldsB0);
  load_lds16(gB1,      ldsB0 + 8192);
  __syncthreads();

  const int nIter = KD / 32;
  for (int it = 0; it < nIter; ++it) {
    const int cur = it & 1, nxt = cur ^ 1;
    if (it + 1 < nIter) {               // prefetch next tile into other buf
      const int k1 = (it + 1) * 32;
      load_lds16(gA  + k1, ldsA  + nxt * 8192);
      load_lds16(gB0 + k1, ldsB0 + nxt * 16384);
      load_lds16(gB1 + k1, ldsB0 + nxt * 16384 + 8192);
    }
    const __hip_bfloat16* Acur = As + cur * 4096;   // elements
    const __hip_bfloat16* Bcur = Bs + cur * 8192;
    bf16x8 af[4], bfr[4];
#pragma unroll
    for (int m = 0; m < 4; ++m)
      af[m] = *(const bf16x8*)(Acur + (wr * 64 + m * 16 + la) * 32 + lk * 8);
#pragma unroll
    for (int n = 0; n < 4; ++n)
      bfr[n] = *(const bf16x8*)(Bcur + (wc * 64 + n * 16 + la) * 32 + lk * 8);
#pragma unroll
    for (int m = 0; m < 4; ++m)
#pragma unroll
      for (int n = 0; n < 4; ++n)
        acc[m][n] = __builtin_amdgcn_mfma_f32_16x16x32_bf16(
            af[m], bfr[n], acc[m][n], 0, 0, 0);
    __syncthreads();   // drains prefetch (vmcnt) + reads done (lgkm) + barrier
  }

  const int rowBase = bm * 128 + wr * 64 + lk * 4;
#pragma unroll
  for (int n = 0; n < 4; ++n) {
    const int col = wc * 64 + n * 16 + la;   // 0..255 (full N in-block)
    const float bs = bias[col];
    float ls = 0.f, ls2 = 0.f;
#pragma unroll
    for (int m = 0; m < 4; ++m) {
      const int row = rowBase + m * 16;
#pragma unroll
      for (int j = 0; j < 4; ++j) {
        float v = acc[m][n][j] + bs;
        v = fmaxf(v, 0.f);
        ls += v; ls2 += v * v;
        out[(size_t)(row + j) * 256 + col] = __float2bfloat16(v);
      }
    }
    atomicAdd(&ssum[col], ls);
    atomicAdd(&ssq[col], ls2);
  }
  __syncthreads();
  if (tid < 256) {
    atomicAdd(&gsum[tid], ssum[tid]);
    atomicAdd(&gsq[tid], ssq[tid]);
  }
}

// ---------------------------------------------------------------------------
// bn apply (with inlined BN2 finalize): read bf16 z2, write f32 out.
// ---------------------------------------------------------------------------
__global__ __launch_bounds__(256) void bn_apply_kernel(
    const __hip_bfloat16* __restrict__ Z, const float* __restrict__ stats,
    const float* __restrict__ g2, const float* __restrict__ be2,
    float* __restrict__ out) {
  __shared__ float ssc[256], ssh[256];
  const int t = threadIdx.x;
  {
    const float m = stats[t] * (1.f / MROWS);
    const float var = stats[256 + t] * (1.f / MROWS) - m * m;
    const float sc = g2[t] * rsqrtf(var + BN_EPS);
    ssc[t] = sc;
    ssh[t] = be2[t] - m * sc;
  }
  __syncthreads();
  const size_t i8 = (size_t)blockIdx.x * 256 + t;  // 8-elem index
  const uint4 raw = ((const uint4*)Z)[i8];
  const int c0 = (int)((i8 * 8) & 255);
  const float4 scA = *(const float4*)(ssc + c0);
  const float4 scB = *(const float4*)(ssc + c0 + 4);
  const float4 shA = *(const float4*)(ssh + c0);
  const float4 shB = *(const float4*)(ssh + c0 + 4);
  float4 oa, ob;
  oa.x = bfu2f((unsigned short)(raw.x & 0xffff)) * scA.x + shA.x;
  oa.y = bfu2f((unsigned short)(raw.x >> 16))    * scA.y + shA.y;
  oa.z = bfu2f((unsigned short)(raw.y & 0xffff)) * scA.z + shA.z;
  oa.w = bfu2f((unsigned short)(raw.y >> 16))    * scA.w + shA.w;
  ob.x = bfu2f((unsigned short)(raw.z & 0xffff)) * scB.x + shB.x;
  ob.y = bfu2f((unsigned short)(raw.z >> 16))    * scB.y + shB.y;
  ob.z = bfu2f((unsigned short)(raw.w & 0xffff)) * scB.z + shB.z;
  ob.w = bfu2f((unsigned short)(raw.w >> 16))    * scB.w + shB.w;
  ((float4*)(out))[i8 * 2]     = oa;
  ((float4*)(out))[i8 * 2 + 1] = ob;
}

// ---------------------------------------------------------------------------
extern "C" void kernel_launch(void* const* d_in, const int* in_sizes, int n_in,
                              void* d_out, int out_size, void* d_ws,
                              size_t ws_size, hipStream_t stream) {
  (void)in_sizes; (void)n_in; (void)out_size; (void)ws_size;
  const float* x        = (const float*)d_in[0];
  const float* pos      = (const float*)d_in[1];
  const float* x_skip   = (const float*)d_in[3];
  const float* pos_skip = (const float*)d_in[4];
  const float* W1  = (const float*)d_in[6];
  const float* b1  = (const float*)d_in[7];
  const float* g1  = (const float*)d_in[8];
  const float* be1 = (const float*)d_in[9];
  const float* W2  = (const float*)d_in[10];
  const float* b2  = (const float*)d_in[11];
  const float* g2  = (const float*)d_in[12];
  const float* be2 = (const float*)d_in[13];
  float* out = (float*)d_out;

  char* ws = (char*)d_ws;
  // Workspace layout (bytes); z2 aliases h0 (h0 dead after gemm1)
  __hip_bfloat16* h0  = (__hip_bfloat16*)(ws);                    // 50331648
  __hip_bfloat16* z2  = (__hip_bfloat16*)(ws);                    // 33554432
  __hip_bfloat16* W1t = (__hip_bfloat16*)(ws + 50331648);         // 196608
  __hip_bfloat16* z1  = (__hip_bfloat16*)(ws + 50528256);         // 33554432
  __hip_bfloat16* W2t = (__hip_bfloat16*)(ws + 84082688);         // 131072
  float* b2p    = (float*)(ws + 84213760);                        // 1024
  float* stats  = (float*)(ws + 84214784);                        // 4096

  knn_interp_kernel<<<1408, 512, 0, stream>>>(x, pos, x_skip, pos_skip, h0,
                                              W1, W1t, stats);
  gemm_bias_relu<DIN><<<512, 512, 0, stream>>>(h0, W1t, b1, z1,
                                               stats, stats + 256);
  prep_w2b2_kernel<<<256, 256, 0, stream>>>(W2, stats, g1, be1, b2, W2t, b2p);
  gemm_bias_relu<CHID><<<512, 512, 0, stream>>>(z1, W2t, b2p, z2,
                                                stats + 512, stats + 768);
  bn_apply_kernel<<<8192, 256, 0, stream>>>(z2, stats + 512, g2, be2, out);
}